// Round 5
// baseline (78.018 us; speedup 1.0000x reference)
//
#include <hip/hip_runtime.h>
#include <hip/hip_bf16.h>

#define LN_EPS 1e-5f
#define S2LE 2.885390081777927f   // 2*log2(e)
#define L2E  1.4426950408889634f  // log2(e)
#define XST 68                    // LDS row stride for x tile (bank spread)

typedef __attribute__((ext_vector_type(8))) short bf16x8;
typedef __attribute__((ext_vector_type(4))) float f32x4;

__device__ __forceinline__ float wsum(float v) {
    #pragma unroll
    for (int off = 32; off; off >>= 1) v += __shfl_xor(v, off, 64);
    return v;
}
__device__ __forceinline__ float wmax(float v) {
    #pragma unroll
    for (int off = 32; off; off >>= 1) v = fmaxf(v, __shfl_xor(v, off, 64));
    return v;
}
// 8x f32 -> bf16 (RNE) via v_cvt_pk_bf16_f32 (compiler-lowered)
__device__ __forceinline__ bf16x8 pack8(float4 a, float4 b) {
    __hip_bfloat162 h0 = __float22bfloat162_rn(float2{a.x, a.y});
    __hip_bfloat162 h1 = __float22bfloat162_rn(float2{a.z, a.w});
    __hip_bfloat162 h2 = __float22bfloat162_rn(float2{b.x, b.y});
    __hip_bfloat162 h3 = __float22bfloat162_rn(float2{b.z, b.w});
    short2 s0 = *reinterpret_cast<short2*>(&h0);
    short2 s1 = *reinterpret_cast<short2*>(&h1);
    short2 s2 = *reinterpret_cast<short2*>(&h2);
    short2 s3 = *reinterpret_cast<short2*>(&h3);
    bf16x8 r;
    r[0] = s0.x; r[1] = s0.y; r[2] = s1.x; r[3] = s1.y;
    r[4] = s2.x; r[5] = s2.y; r[6] = s3.x; r[7] = s3.y;
    return r;
}
__device__ __forceinline__ float fexp2(float x) {
#if __has_builtin(__builtin_amdgcn_exp2f)
    return __builtin_amdgcn_exp2f(x);
#else
    return exp2f(x);
#endif
}
__device__ __forceinline__ float frcp(float x) {
#if __has_builtin(__builtin_amdgcn_rcpf)
    return __builtin_amdgcn_rcpf(x);
#else
    return 1.f / x;
#endif
}

// ================= prep: 769 blocks x 256 threads, roles by blockIdx =================
// blocks 0..511   : ai/aj (16 rows each), prescaled by S2LE
// blocks 512..767 : afrag pack (4 fragment-slots per block)
// block 768       : Tf (frag-ordered, d-interleaved g*Wij), Sx, c2, consts[0]
__global__ __launch_bounds__(256) void att1_prep(
    const float* __restrict__ emb, const float* __restrict__ g,
    const float* __restrict__ bln, const float* __restrict__ W1,
    const float* __restrict__ b1, const float* __restrict__ W2,
    const float* __restrict__ b2, float* __restrict__ ai,
    float* __restrict__ aj, short* __restrict__ afrag,
    float* __restrict__ Tf, float* __restrict__ Sx,
    float* __restrict__ c2, float* __restrict__ consts)
{
    const int bid = blockIdx.x, tid = threadIdx.x, lane = tid & 63, wid = tid >> 6;
    if (bid < 512) {
        __shared__ float w_s[8192];
        __shared__ float xn_s[4][64];
        for (int i = tid * 4; i < 8192; i += 1024)
            *(float4*)&w_s[i] = *(const float4*)&W1[i];
        __syncthreads();
        #pragma unroll
        for (int it = 0; it < 4; ++it) {
            const int r = bid * 16 + it * 4 + wid;
            float x = emb[r * 64 + lane];
            float m = wsum(x) * (1.f / 64.f);
            float xc = x - m;
            float var = wsum(xc * xc) * (1.f / 64.f);
            float xn = xc * rsqrtf(var + LN_EPS) * g[lane] + bln[lane];
            xn_s[wid][lane] = xn;          // same-wave write->read
            float a0 = 0.f, a1 = 0.f;
            #pragma unroll
            for (int k = 0; k < 64; ++k) {
                float xnk = xn_s[wid][k];
                a0 = fmaf(xnk, w_s[k * 64 + lane], a0);
                a1 = fmaf(xnk, w_s[(64 + k) * 64 + lane], a1);
            }
            ai[r * 64 + lane] = a0 * S2LE;
            aj[r * 64 + lane] = a1 * S2LE;
        }
    } else if (bid < 768) {
        const int id = (bid - 512) * 4 + wid;      // b*16 + qt*2 + h
        const int h = id & 1, qt = (id >> 1) & 7, bb = id >> 4;
        const int q = 16 * qt + (lane & 15);
        const int k = 32 * h + 8 * (lane >> 4);
        const float* src = emb + (bb * 128 + q) * 64 + k;
        float4 v0 = ((const float4*)src)[0];
        float4 v1 = ((const float4*)src)[1];
        *(bf16x8*)(afrag + (size_t)(id * 64 + lane) * 8) = pack8(v0, v1);
    } else {
        for (int slot = tid; slot < 512; slot += 256) {   // (dt*2+h)*64 + l
            int l = slot & 63, h = (slot >> 6) & 1, dt = slot >> 7;
            int n = 4 * (l & 15) + dt;                    // d-interleaved column
            int k = 32 * h + 8 * (l >> 4);
            #pragma unroll
            for (int j = 0; j < 8; ++j)
                Tf[slot * 8 + j] = g[k + j] * W1[(128 + k + j) * 64 + n];
        }
        if (tid < 64) {
            float S = 0.f, c = 0.f;
            for (int k = 0; k < 64; ++k) {
                float w = W1[(128 + k) * 64 + tid];
                S = fmaf(g[k], w, S);
                c = fmaf(bln[k], w, c);
            }
            Sx[tid] = S;
            c2[tid] = (c + b1[tid]) * S2LE;
            if (tid == 0) {
                float sw = 0.f;
                for (int d = 0; d < 64; ++d) sw += W2[d];
                consts[0] = sw + b2[0];
            }
        }
    }
}

// ================= main: block per (b, p-pair), 8 waves; 2 p's sequentially =========
__global__ __launch_bounds__(512) void att1_main(
    const float* __restrict__ emb, const short* __restrict__ afrag,
    const float* __restrict__ Tf, const float* __restrict__ Sx,
    const float* __restrict__ c2a, const float* __restrict__ W2,
    const float* __restrict__ consts, const float* __restrict__ ai,
    const float* __restrict__ aj, float* __restrict__ out)
{
    __shared__ float xb_s[128 * XST];      // 34 KB
    __shared__ bf16x8 bfr_s[512];          // 8 KB
    __shared__ float mu_s[128], rs_s[128];
    __shared__ float scores_s[128], alpha_s[128];
    __shared__ float red1_s[8][64], red2_s[8][64];

    const int tid = threadIdx.x, lane = tid & 63, w = tid >> 6;
    const int b = blockIdx.y;
    const float* embB = emb + b * 8192;

    // A fragments (p-invariant; reused for both p's)
    bf16x8 afr0 = *(const bf16x8*)(afrag + (size_t)((b * 16 + 2 * w + 0) * 64 + lane) * 8);
    bf16x8 afr1 = *(const bf16x8*)(afrag + (size_t)((b * 16 + 2 * w + 1) * 64 + lane) * 8);

    // stage emb[b] into LDS (stride 68)
    {
        const int r0 = tid >> 4, c0 = (tid & 15) * 4;
        #pragma unroll
        for (int pass = 0; pass < 4; ++pass) {
            int r = r0 + pass * 32;
            *(float4*)&xb_s[r * XST + c0] = *(const float4*)&embB[r * 64 + c0];
        }
    }

    // p-invariant per-thread constants (d-quad d0..d0+3 under interleaved layout)
    const int g4 = lane >> 4, dl = lane & 15;
    const int q0 = 16 * w + 4 * g4;
    const int d0 = 4 * dl;
    float4 S4f = *(const float4*)(Sx + d0);
    float4 c2f = *(const float4*)(c2a + d0);
    float4 w2f = *(const float4*)(W2 + d0);
    float S4[4]   = {S4f.x, S4f.y, S4f.z, S4f.w};
    float w2m2[4] = {-2.f * w2f.x, -2.f * w2f.y, -2.f * w2f.z, -2.f * w2f.w};
    const float sw2b2 = consts[0];

    // Tf registers (p-invariant)
    const int k0 = 32 * ((tid >> 6) & 1) + 8 * ((tid >> 4) & 3);
    const float4* tf = (const float4*)(Tf + (size_t)tid * 8);
    float4 t0 = tf[0], t1 = tf[1];

    __syncthreads();

    for (int pi = 0; pi < 2; ++pi) {
        const int p = blockIdx.x * 2 + pi;
        const int bp = b * 128 + p;

        // --- B-build: one U fragment per thread (cvt_pk packing)
        {
            const float* xr = &xb_s[p * XST + k0];
            float4 x0 = *(const float4*)xr, x1 = *(const float4*)(xr + 4);
            float4 u0 = {t0.x * x0.x, t0.y * x0.y, t0.z * x0.z, t0.w * x0.w};
            float4 u1 = {t1.x * x1.x, t1.y * x1.y, t1.z * x1.z, t1.w * x1.w};
            bfr_s[tid] = pack8(u0, u1);
        }

        // --- stats: pair q = tid>>2, k-quarter c = tid&3 (f32 exact)
        {
            const int q = tid >> 2, c = tid & 3;
            const float* xq = &xb_s[q * XST + c * 16];
            const float* xp = &xb_s[p * XST + c * 16];
            float s = 0.f, s2 = 0.f;
            #pragma unroll
            for (int j = 0; j < 4; ++j) {
                float4 a = *(const float4*)(xp + j * 4);
                float4 d = *(const float4*)(xq + j * 4);
                float p0 = a.x * d.x, p1 = a.y * d.y, p2 = a.z * d.z, p3 = a.w * d.w;
                s += p0 + p1 + p2 + p3;
                s2 = fmaf(p0, p0, fmaf(p1, p1, fmaf(p2, p2, fmaf(p3, p3, s2))));
            }
            s  += __shfl_xor(s, 1, 64);  s  += __shfl_xor(s, 2, 64);
            s2 += __shfl_xor(s2, 1, 64); s2 += __shfl_xor(s2, 2, 64);
            if (c == 0) {
                float m = s * (1.f / 64.f);
                float var = fmaxf(s2 * (1.f / 64.f) - m * m, 0.f);
                mu_s[q] = m;
                rs_s[q] = rsqrtf(var + LN_EPS) * S2LE;
            }
        }
        __syncthreads();   // S1

        // --- MFMA: raw[q-tile w, d = 0..63 interleaved]
        bf16x8 bfr[4][2];
        #pragma unroll
        for (int dt = 0; dt < 4; ++dt)
            #pragma unroll
            for (int h = 0; h < 2; ++h)
                bfr[dt][h] = bfr_s[(dt * 2 + h) * 64 + lane];

        f32x4 acc[4];
        #pragma unroll
        for (int dt = 0; dt < 4; ++dt) {
            f32x4 c = {0.f, 0.f, 0.f, 0.f};
            c = __builtin_amdgcn_mfma_f32_16x16x32_bf16(afr0, bfr[dt][0], c, 0, 0, 0);
            c = __builtin_amdgcn_mfma_f32_16x16x32_bf16(afr1, bfr[dt][1], c, 0, 0, 0);
            acc[dt] = c;
        }

        // --- epilogue. acc[dt][r]: q = q0+r, d = d0+dt (consecutive!)
        float4 mu4 = *(const float4*)&mu_s[q0];
        float4 rs4 = *(const float4*)&rs_s[q0];
        float muA[4] = {mu4.x, mu4.y, mu4.z, mu4.w};
        float rsA[4] = {rs4.x, rs4.y, rs4.z, rs4.w};
        float4 ajf = *(const float4*)(aj + (size_t)bp * 64 + d0);
        float ajc[4] = {ajf.x + c2f.x, ajf.y + c2f.y, ajf.z + c2f.z, ajf.w + c2f.w};
        float rmu[4];
        #pragma unroll
        for (int r = 0; r < 4; ++r) rmu[r] = rsA[r] * muA[r];

        const float* aibase = ai + (size_t)(b * 128 + q0) * 64 + d0;
        float part[4];
        #pragma unroll
        for (int r = 0; r < 4; ++r) {
            float4 aif = *(const float4*)(aibase + r * 64);
            float aiv[4] = {aif.x, aif.y, aif.z, aif.w};
            float pr = 0.f;
            #pragma unroll
            for (int dt = 0; dt < 4; ++dt) {
                float xv = fmaf(rsA[r], acc[dt][r], fmaf(-rmu[r], S4[dt], ajc[dt]) + aiv[dt]);
                float e = fexp2(xv);
                pr = fmaf(w2m2[dt], frcp(e + 1.f), pr);
            }
            part[r] = pr;
        }
        #pragma unroll
        for (int r = 0; r < 4; ++r) {
            #pragma unroll
            for (int off = 1; off <= 8; off <<= 1)
                part[r] += __shfl_xor(part[r], off, 64);
        }
        if (dl == 0) {
            float4 sc = {part[0] + sw2b2, part[1] + sw2b2, part[2] + sw2b2, part[3] + sw2b2};
            *(float4*)&scores_s[q0] = sc;
        }
        __syncthreads();   // S2

        // --- softmax + alpha (waves 0,1)
        if (w < 2) {
            float s0 = scores_s[lane], s1 = scores_s[64 + lane];
            float M = wmax(fmaxf(s0, s1));
            float Z = wsum(fexp2((s0 - M) * L2E) + fexp2((s1 - M) * L2E));
            float rZ = frcp(Z);
            float sown = (w == 0) ? s0 : s1;
            alpha_s[tid] = fexp2((sown - M) * L2E) * rZ;
        }
        __syncthreads();   // S3

        // --- ctx via lrelu(v) = 0.505 v + 0.495 |v|
        float s1acc = 0.f, s2acc = 0.f;
        #pragma unroll
        for (int i = 0; i < 16; ++i) {
            int q = 16 * w + i;
            float al = alpha_s[q];
            float xq = xb_s[q * XST + lane];
            s1acc = fmaf(al, xq, s1acc);
            s2acc = fmaf(al, fabsf(xq), s2acc);
        }
        red1_s[w][lane] = s1acc;
        red2_s[w][lane] = s2acc;
        __syncthreads();   // S4

        if (w == 0) {
            float S1 = 0.f, S2 = 0.f;
            #pragma unroll
            for (int j = 0; j < 8; ++j) { S1 += red1_s[j][lane]; S2 += red2_s[j][lane]; }
            float xp = xb_s[p * XST + lane];
            out[(size_t)bp * 64 + lane] = fmaf(0.505f * xp, S1, 0.495f * fabsf(xp) * S2);
        }
    }
}

extern "C" void kernel_launch(void* const* d_in, const int* in_sizes, int n_in,
                              void* d_out, int out_size, void* d_ws, size_t ws_size,
                              hipStream_t stream) {
    const float* emb = (const float*)d_in[0];   // [64,128,64]
    const float* g   = (const float*)d_in[1];   // [64]
    const float* bln = (const float*)d_in[2];   // [64]
    const float* W1  = (const float*)d_in[3];   // [192,64]
    const float* b1  = (const float*)d_in[4];   // [64]
    const float* W2  = (const float*)d_in[5];   // [64,1]
    const float* b2  = (const float*)d_in[6];   // [1]
    float* out = (float*)d_out;

    float* ws = (float*)d_ws;
    float* ai = ws;                      // 524288 f
    float* aj = ws + 524288;             // 524288 f
    float* Tf = ws + 1048576;            // 4096 f
    float* Sx = ws + 1052672;            // 64 f
    float* c2 = ws + 1052736;            // 64 f
    float* consts = ws + 1052800;        // 64 f (1 used)
    short* af = (short*)(ws + 1052864);  // 524288 bf16 (1 MB)

    att1_prep<<<769, 256, 0, stream>>>(emb, g, bln, W1, b1, W2, b2,
                                       ai, aj, af, Tf, Sx, c2, consts);
    att1_main<<<dim3(64, 64), 512, 0, stream>>>(emb, af, Tf, Sx, c2, W2, consts,
                                                ai, aj, out);
}

// Round 6
// 59.340 us; speedup vs baseline: 1.3148x; 1.3148x over previous
//
#include <hip/hip_runtime.h>
#include <hip/hip_bf16.h>

#define LN_EPS 1e-5f
#define S2LE 2.885390081777927f   // 2*log2(e)
#define L2E  1.4426950408889634f  // log2(e)
#define XST 68                    // LDS row stride (17 dwords -> odd bank step)

typedef __attribute__((ext_vector_type(8))) short bf16x8;
typedef __attribute__((ext_vector_type(4))) float f32x4;

__device__ __forceinline__ float wsum(float v) {
    #pragma unroll
    for (int off = 32; off; off >>= 1) v += __shfl_xor(v, off, 64);
    return v;
}
__device__ __forceinline__ float wmax(float v) {
    #pragma unroll
    for (int off = 32; off; off >>= 1) v = fmaxf(v, __shfl_xor(v, off, 64));
    return v;
}
// 8x f32 -> bf16 (RNE) via v_cvt_pk_bf16_f32 (compiler-lowered)
__device__ __forceinline__ bf16x8 pack8(float4 a, float4 b) {
    __hip_bfloat162 h0 = __float22bfloat162_rn(float2{a.x, a.y});
    __hip_bfloat162 h1 = __float22bfloat162_rn(float2{a.z, a.w});
    __hip_bfloat162 h2 = __float22bfloat162_rn(float2{b.x, b.y});
    __hip_bfloat162 h3 = __float22bfloat162_rn(float2{b.z, b.w});
    short2 s0 = *reinterpret_cast<short2*>(&h0);
    short2 s1 = *reinterpret_cast<short2*>(&h1);
    short2 s2 = *reinterpret_cast<short2*>(&h2);
    short2 s3 = *reinterpret_cast<short2*>(&h3);
    bf16x8 r;
    r[0] = s0.x; r[1] = s0.y; r[2] = s1.x; r[3] = s1.y;
    r[4] = s2.x; r[5] = s2.y; r[6] = s3.x; r[7] = s3.y;
    return r;
}
__device__ __forceinline__ float fexp2(float x) {
#if __has_builtin(__builtin_amdgcn_exp2f)
    return __builtin_amdgcn_exp2f(x);
#else
    return exp2f(x);
#endif
}
__device__ __forceinline__ float frcp(float x) {
#if __has_builtin(__builtin_amdgcn_rcpf)
    return __builtin_amdgcn_rcpf(x);
#else
    return 1.f / x;
#endif
}

// ================= prep: 769 blocks x 256 threads, roles by blockIdx =================
// blocks 0..511   : ai/aj (16 rows each), prescaled by S2LE
// blocks 512..767 : afrag pack (4 fragment-slots per block)
// block 768       : Tf (frag-ordered, d-interleaved g*Wij), Sx, c2, consts[0]
__global__ __launch_bounds__(256) void att1_prep(
    const float* __restrict__ emb, const float* __restrict__ g,
    const float* __restrict__ bln, const float* __restrict__ W1,
    const float* __restrict__ b1, const float* __restrict__ W2,
    const float* __restrict__ b2, float* __restrict__ ai,
    float* __restrict__ aj, short* __restrict__ afrag,
    float* __restrict__ Tf, float* __restrict__ Sx,
    float* __restrict__ c2, float* __restrict__ consts)
{
    const int bid = blockIdx.x, tid = threadIdx.x, lane = tid & 63, wid = tid >> 6;
    if (bid < 512) {
        __shared__ float w_s[8192];
        __shared__ float xn_s[4][64];
        for (int i = tid * 4; i < 8192; i += 1024)
            *(float4*)&w_s[i] = *(const float4*)&W1[i];
        __syncthreads();
        #pragma unroll
        for (int it = 0; it < 4; ++it) {
            const int r = bid * 16 + it * 4 + wid;
            float x = emb[r * 64 + lane];
            float m = wsum(x) * (1.f / 64.f);
            float xc = x - m;
            float var = wsum(xc * xc) * (1.f / 64.f);
            float xn = xc * rsqrtf(var + LN_EPS) * g[lane] + bln[lane];
            xn_s[wid][lane] = xn;          // same-wave write->read
            float a0 = 0.f, a1 = 0.f;
            #pragma unroll
            for (int k = 0; k < 64; ++k) {
                float xnk = xn_s[wid][k];
                a0 = fmaf(xnk, w_s[k * 64 + lane], a0);
                a1 = fmaf(xnk, w_s[(64 + k) * 64 + lane], a1);
            }
            ai[r * 64 + lane] = a0 * S2LE;
            aj[r * 64 + lane] = a1 * S2LE;
        }
    } else if (bid < 768) {
        const int id = (bid - 512) * 4 + wid;      // b*16 + qt*2 + h
        const int h = id & 1, qt = (id >> 1) & 7, bb = id >> 4;
        const int q = 16 * qt + (lane & 15);
        const int k = 32 * h + 8 * (lane >> 4);
        const float* src = emb + (bb * 128 + q) * 64 + k;
        float4 v0 = ((const float4*)src)[0];
        float4 v1 = ((const float4*)src)[1];
        *(bf16x8*)(afrag + (size_t)(id * 64 + lane) * 8) = pack8(v0, v1);
    } else {
        for (int slot = tid; slot < 512; slot += 256) {   // (dt*2+h)*64 + l
            int l = slot & 63, h = (slot >> 6) & 1, dt = slot >> 7;
            int n = 4 * (l & 15) + dt;                    // d-interleaved column
            int k = 32 * h + 8 * (l >> 4);
            #pragma unroll
            for (int j = 0; j < 8; ++j)
                Tf[slot * 8 + j] = g[k + j] * W1[(128 + k + j) * 64 + n];
        }
        if (tid < 64) {
            float S = 0.f, c = 0.f;
            for (int k = 0; k < 64; ++k) {
                float w = W1[(128 + k) * 64 + tid];
                S = fmaf(g[k], w, S);
                c = fmaf(bln[k], w, c);
            }
            Sx[tid] = S;
            c2[tid] = (c + b1[tid]) * S2LE;
            if (tid == 0) {
                float sw = 0.f;
                for (int d = 0; d < 64; ++d) sw += W2[d];
                consts[0] = sw + b2[0];
            }
        }
    }
}

// ================= main: block = (b, 8 p's); wave w owns p = 8*bx + w end-to-end.
// Single barrier (after staging). All other sequencing is in-wave (DS ops in order).
__global__ __launch_bounds__(512) void att1_main(
    const float* __restrict__ emb, const short* __restrict__ afrag,
    const float* __restrict__ Tf, const float* __restrict__ Sx,
    const float* __restrict__ c2a, const float* __restrict__ W2,
    const float* __restrict__ consts, const float* __restrict__ ai,
    const float* __restrict__ aj, float* __restrict__ out)
{
    __shared__ float xb_s[128 * XST];      // 34816 B
    __shared__ float muWS[8][128];         // 4 KB (per-wave)
    __shared__ float rsWS[8][128];         // 4 KB
    __shared__ float scWS[8][128];         // 4 KB (scores, then alphas in-place)

    const int tid = threadIdx.x, lane = tid & 63, w = tid >> 6;
    const int b = blockIdx.y;
    const int p = blockIdx.x * 8 + w;
    const int bp = b * 128 + p;
    const float* embB = emb + b * 8192;

    // stage emb[b] into LDS (stride 68)
    {
        const int r0 = tid >> 4, c0 = (tid & 15) * 4;
        #pragma unroll
        for (int pass = 0; pass < 4; ++pass) {
            int r = r0 + pass * 32;
            *(float4*)&xb_s[r * XST + c0] = *(const float4*)&embB[r * 64 + c0];
        }
    }
    __syncthreads();   // the only block barrier

    const int g4 = lane >> 4, dl = lane & 15;
    const int d0 = 4 * dl;

    // per-thread constants (d-quad d0..d0+3 under interleaved layout)
    float4 S4f = *(const float4*)(Sx + d0);
    float4 c2f = *(const float4*)(c2a + d0);
    float4 w2f = *(const float4*)(W2 + d0);
    float S4[4]   = {S4f.x, S4f.y, S4f.z, S4f.w};
    float w2m2[4] = {-2.f * w2f.x, -2.f * w2f.y, -2.f * w2f.z, -2.f * w2f.w};
    const float sw2b2 = consts[0];
    float4 ajf = *(const float4*)(aj + (size_t)bp * 64 + d0);
    float ajc[4] = {ajf.x + c2f.x, ajf.y + c2f.y, ajf.z + c2f.z, ajf.w + c2f.w};

    // --- B-build (wave-private): 8 fragments of U[k,d] = x_p[k]*T[k,d]
    bf16x8 bfr[4][2];
    #pragma unroll
    for (int h = 0; h < 2; ++h) {
        const float* xr = &xb_s[p * XST + 32 * h + 8 * g4];
        float4 x0 = *(const float4*)xr, x1 = *(const float4*)(xr + 4);
        #pragma unroll
        for (int dt = 0; dt < 4; ++dt) {
            const float4* tf = (const float4*)(Tf + (size_t)((dt * 2 + h) * 64 + lane) * 8);
            float4 t0 = tf[0], t1 = tf[1];
            float4 u0 = {t0.x * x0.x, t0.y * x0.y, t0.z * x0.z, t0.w * x0.w};
            float4 u1 = {t1.x * x1.x, t1.y * x1.y, t1.z * x1.z, t1.w * x1.w};
            bfr[dt][h] = pack8(u0, u1);
        }
    }

    // --- stats (wave-private): lane does q = lane and q = lane+64 (f32 exact)
    {
        const float* xpr = &xb_s[p * XST];
        const float* xqa = &xb_s[lane * XST];
        const float* xqb = &xb_s[(64 + lane) * XST];
        float sa = 0.f, sa2 = 0.f, sb = 0.f, sb2 = 0.f;
        #pragma unroll
        for (int j = 0; j < 16; ++j) {
            float4 a = *(const float4*)(xpr + 4 * j);
            float4 qa = *(const float4*)(xqa + 4 * j);
            float4 qb = *(const float4*)(xqb + 4 * j);
            float a0 = a.x * qa.x, a1 = a.y * qa.y, a2 = a.z * qa.z, a3 = a.w * qa.w;
            sa += a0 + a1 + a2 + a3;
            sa2 = fmaf(a0, a0, fmaf(a1, a1, fmaf(a2, a2, fmaf(a3, a3, sa2))));
            float b0 = a.x * qb.x, b1v = a.y * qb.y, b2v = a.z * qb.z, b3 = a.w * qb.w;
            sb += b0 + b1v + b2v + b3;
            sb2 = fmaf(b0, b0, fmaf(b1v, b1v, fmaf(b2v, b2v, fmaf(b3, b3, sb2))));
        }
        float ma = sa * (1.f / 64.f);
        float va = fmaxf(sa2 * (1.f / 64.f) - ma * ma, 0.f);
        muWS[w][lane] = ma;
        rsWS[w][lane] = rsqrtf(va + LN_EPS) * S2LE;
        float mb = sb * (1.f / 64.f);
        float vb = fmaxf(sb2 * (1.f / 64.f) - mb * mb, 0.f);
        muWS[w][64 + lane] = mb;
        rsWS[w][64 + lane] = rsqrtf(vb + LN_EPS) * S2LE;
    }

    // --- q-tile loop: MFMA + score epilogue (all wave-private)
    #pragma unroll 2
    for (int qt = 0; qt < 8; ++qt) {
        bf16x8 afr0 = *(const bf16x8*)(afrag + (size_t)((b * 16 + 2 * qt + 0) * 64 + lane) * 8);
        bf16x8 afr1 = *(const bf16x8*)(afrag + (size_t)((b * 16 + 2 * qt + 1) * 64 + lane) * 8);
        f32x4 acc[4];
        #pragma unroll
        for (int dt = 0; dt < 4; ++dt) {
            f32x4 c = {0.f, 0.f, 0.f, 0.f};
            c = __builtin_amdgcn_mfma_f32_16x16x32_bf16(afr0, bfr[dt][0], c, 0, 0, 0);
            c = __builtin_amdgcn_mfma_f32_16x16x32_bf16(afr1, bfr[dt][1], c, 0, 0, 0);
            acc[dt] = c;
        }

        const int q0 = 16 * qt + 4 * g4;
        float4 mu4 = *(const float4*)&muWS[w][q0];
        float4 rs4 = *(const float4*)&rsWS[w][q0];
        float muA[4] = {mu4.x, mu4.y, mu4.z, mu4.w};
        float rsA[4] = {rs4.x, rs4.y, rs4.z, rs4.w};

        const float* aibase = ai + (size_t)(b * 128 + q0) * 64 + d0;
        float part[4];
        #pragma unroll
        for (int r = 0; r < 4; ++r) {
            float4 aif = *(const float4*)(aibase + r * 64);
            float aiv[4] = {aif.x, aif.y, aif.z, aif.w};
            float rmu = rsA[r] * muA[r];
            float pr = 0.f;
            #pragma unroll
            for (int dt = 0; dt < 4; ++dt) {
                float xv = fmaf(rsA[r], acc[dt][r], fmaf(-rmu, S4[dt], ajc[dt]) + aiv[dt]);
                float e = fexp2(xv);
                pr = fmaf(w2m2[dt], frcp(e + 1.f), pr);
            }
            part[r] = pr;
        }
        #pragma unroll
        for (int r = 0; r < 4; ++r) {
            #pragma unroll
            for (int off = 1; off <= 8; off <<= 1)
                part[r] += __shfl_xor(part[r], off, 64);
        }
        if (dl == 0) {
            float4 sc = {part[0] + sw2b2, part[1] + sw2b2, part[2] + sw2b2, part[3] + sw2b2};
            *(float4*)&scWS[w][q0] = sc;
        }
    }

    // --- softmax (wave-private; alphas overwrite scores in place)
    {
        float s0 = scWS[w][lane], s1 = scWS[w][64 + lane];
        float M = wmax(fmaxf(s0, s1));
        float e0 = fexp2((s0 - M) * L2E), e1 = fexp2((s1 - M) * L2E);
        float rZ = frcp(wsum(e0 + e1));
        scWS[w][lane] = e0 * rZ;
        scWS[w][64 + lane] = e1 * rZ;
    }

    // --- ctx (d-vectorized): lane owns d-quad d0, q-subset {4i + g4}
    {
        float4 S1 = {0.f, 0.f, 0.f, 0.f}, S2 = {0.f, 0.f, 0.f, 0.f};
        #pragma unroll 8
        for (int i = 0; i < 32; ++i) {
            int q = 4 * i + g4;
            float al = scWS[w][q];
            float4 xq = *(const float4*)&xb_s[q * XST + d0];
            S1.x = fmaf(al, xq.x, S1.x); S1.y = fmaf(al, xq.y, S1.y);
            S1.z = fmaf(al, xq.z, S1.z); S1.w = fmaf(al, xq.w, S1.w);
            S2.x = fmaf(al, fabsf(xq.x), S2.x); S2.y = fmaf(al, fabsf(xq.y), S2.y);
            S2.z = fmaf(al, fabsf(xq.z), S2.z); S2.w = fmaf(al, fabsf(xq.w), S2.w);
        }
        #pragma unroll
        for (int off = 16; off <= 32; off <<= 1) {
            S1.x += __shfl_xor(S1.x, off, 64); S1.y += __shfl_xor(S1.y, off, 64);
            S1.z += __shfl_xor(S1.z, off, 64); S1.w += __shfl_xor(S1.w, off, 64);
            S2.x += __shfl_xor(S2.x, off, 64); S2.y += __shfl_xor(S2.y, off, 64);
            S2.z += __shfl_xor(S2.z, off, 64); S2.w += __shfl_xor(S2.w, off, 64);
        }
        if (g4 == 0) {
            float4 xp4 = *(const float4*)&xb_s[p * XST + d0];
            float4 o;
            o.x = fmaf(0.505f * xp4.x, S1.x, 0.495f * fabsf(xp4.x) * S2.x);
            o.y = fmaf(0.505f * xp4.y, S1.y, 0.495f * fabsf(xp4.y) * S2.y);
            o.z = fmaf(0.505f * xp4.z, S1.z, 0.495f * fabsf(xp4.z) * S2.z);
            o.w = fmaf(0.505f * xp4.w, S1.w, 0.495f * fabsf(xp4.w) * S2.w);
            *(float4*)&out[(size_t)bp * 64 + d0] = o;
        }
    }
}

extern "C" void kernel_launch(void* const* d_in, const int* in_sizes, int n_in,
                              void* d_out, int out_size, void* d_ws, size_t ws_size,
                              hipStream_t stream) {
    const float* emb = (const float*)d_in[0];   // [64,128,64]
    const float* g   = (const float*)d_in[1];   // [64]
    const float* bln = (const float*)d_in[2];   // [64]
    const float* W1  = (const float*)d_in[3];   // [192,64]
    const float* b1  = (const float*)d_in[4];   // [64]
    const float* W2  = (const float*)d_in[5];   // [64,1]
    const float* b2  = (const float*)d_in[6];   // [1]
    float* out = (float*)d_out;

    float* ws = (float*)d_ws;
    float* ai = ws;                      // 524288 f
    float* aj = ws + 524288;             // 524288 f
    float* Tf = ws + 1048576;            // 4096 f
    float* Sx = ws + 1052672;            // 64 f
    float* c2 = ws + 1052736;            // 64 f
    float* consts = ws + 1052800;        // 64 f (1 used)
    short* af = (short*)(ws + 1052864);  // 524288 bf16 (1 MB)

    att1_prep<<<769, 256, 0, stream>>>(emb, g, bln, W1, b1, W2, b2,
                                       ai, aj, af, Tf, Sx, c2, consts);
    att1_main<<<dim3(16, 64), 512, 0, stream>>>(emb, af, Tf, Sx, c2, W2, consts,
                                                ai, aj, out);
}